// Round 8
// baseline (137.362 us; speedup 1.0000x reference)
//
#include <hip/hip_runtime.h>
#include <hip/hip_bf16.h>
#include <stdint.h>

#define NROW 4096
#define DIM  512
#define BT   64                        // block tile 64x64
#define BK   32
#define NKT  (DIM / BK)                // 16 k-tiles of 32
#define NT64 (NROW / BT)               // 64
#define NTRI (NT64 * (NT64 + 1) / 2)   // 2080 triangular blocks

typedef __attribute__((ext_vector_type(8))) short  short8;   // 8 bf16 = 4 VGPRs
typedef __attribute__((ext_vector_type(4))) float  floatx4;  // MFMA 16x16 C/D

typedef const __attribute__((address_space(1))) void gvoid_t;
typedef __attribute__((address_space(3))) void       svoid_t;

__device__ __forceinline__ unsigned short f32_to_bf16_rne(float f) {
    unsigned u = __float_as_uint(f);
    u += 0x7FFFu + ((u >> 16) & 1u);
    return (unsigned short)(u >> 16);
}

// kt-major pre-swizzled layout (R7, proven): slab (kt=k/32, G=row/8) of 256
// shorts holds [l3=row%8][p] = 16-B chunk, p = chunk ^ (row&3).  A 64-row
// panel's kt-slab = 8 consecutive slabs = 4 KB contiguous; staging is
// base + tid*16B.  meta[row] = {sq_fp32, bits(y*4+ds)}.
__global__ __launch_bounds__(256) void prep_kernel(
    const float* __restrict__ X, const int* __restrict__ ds,
    const int* __restrict__ y, unsigned short* __restrict__ Xpre,
    float2* __restrict__ meta, float* __restrict__ out)
{
    const int wave = threadIdx.x >> 6;
    const int lane = threadIdx.x & 63;
    const int row  = blockIdx.x * 4 + wave;
    const float4* xr = (const float4*)(X + (size_t)row * DIM);
    float4 v0 = xr[2 * lane];
    float4 v1 = xr[2 * lane + 1];
    float s = v0.x*v0.x + v0.y*v0.y + v0.z*v0.z + v0.w*v0.w
            + v1.x*v1.x + v1.y*v1.y + v1.z*v1.z + v1.w*v1.w;
    uint4 pk;
    pk.x = f32_to_bf16_rne(v0.x) | ((unsigned)f32_to_bf16_rne(v0.y) << 16);
    pk.y = f32_to_bf16_rne(v0.z) | ((unsigned)f32_to_bf16_rne(v0.w) << 16);
    pk.z = f32_to_bf16_rne(v1.x) | ((unsigned)f32_to_bf16_rne(v1.y) << 16);
    pk.w = f32_to_bf16_rne(v1.z) | ((unsigned)f32_to_bf16_rne(v1.w) << 16);
    const int G     = row >> 3;
    const int l3r   = row & 7;
    const int kt32  = lane >> 2;          // lane covers k = lane*8..lane*8+7
    const int chunk = lane & 3;
    const int p     = chunk ^ (row & 3);
    *(uint4*)(Xpre + ((size_t)kt32 * 512 + G) * 256 + l3r * 32 + p * 8) = pk;
    #pragma unroll
    for (int off = 32; off; off >>= 1) s += __shfl_xor(s, off);
    if (lane == 0)
        meta[row] = make_float2(s, __int_as_float(y[row] * 4 + ds[row]));
    if (blockIdx.x == 0 && threadIdx.x < 2) out[threadIdx.x] = 0.0f;
}

// Triangular 64x64 Gram tiles, 128 threads (2 waves, each 64x32 via 4x2
// 16x16x32 MFMAs), BK=32 LDS dbuf (16 KB) + single 2-wave barrier per kt.
// 2080 blocks = ~8 independent barrier-groups per CU: barrier/load-drain
// stalls of one block are covered by 7 others (R1-vs-R5 evidence: block
// independence, not wave count, sets throughput for this latency-bound loop).
__global__ __launch_bounds__(128, 4) void ccsa_kernel(
    const unsigned short* __restrict__ Xpre, const float2* __restrict__ meta,
    const int* __restrict__ ncls, const int* __restrict__ ndom,
    float* __restrict__ out)
{
    __shared__ __align__(16) unsigned short As[2 * BT * BK];  // 8 KB
    __shared__ __align__(16) unsigned short Bs[2 * BT * BK];  // 8 KB
    __shared__ float red[4];

    // triangular decode: block t -> (it <= jt) on the 64-tile lattice
    const int t = blockIdx.x;
    int r = (int)((sqrtf(8.0f * (float)t + 1.0f) - 1.0f) * 0.5f);
    while ((r + 1) * (r + 2) / 2 <= t) ++r;
    while (r * (r + 1) / 2 > t) --r;
    const int jt   = r;
    const int it   = t - r * (r + 1) / 2;
    const bool diag = (it == jt);
    const int bm0 = it * BT;
    const int bn0 = jt * BT;
    const int GA = bm0 >> 3;
    const int GB = bn0 >> 3;

    const int tid  = threadIdx.x;
    const int wave = tid >> 6;          // 0..1 : 32-col band
    const int lane = tid & 63;
    const int m15  = lane & 15;
    const int quad = lane >> 4;

    // j-side metadata, loop-invariant
    float sqj[2]; int yj[2], dj[2];
    #pragma unroll
    for (int tn = 0; tn < 2; ++tn) {
        const float2 mj = meta[bn0 + wave * 32 + tn * 16 + m15];
        sqj[tn] = mj.x;
        const int ydj = __float_as_int(mj.y);
        dj[tn] = ydj & 3; yj[tn] = ydj >> 2;
    }

    floatx4 acc[4][2];
    #pragma unroll
    for (int a = 0; a < 4; ++a)
        #pragma unroll
        for (int b = 0; b < 2; ++b)
            acc[a][b] = (floatx4){0.f, 0.f, 0.f, 0.f};

    // diagonal tiles: A-tile == B-tile; stage once, read B from As.
    const unsigned short* Bbase = diag ? As : Bs;

    // staging: A-panel kt-slab is 4 KB contiguous; 128 threads x 16 B x 2.
    #define STAGE(buf, kt)                                                    \
        do {                                                                  \
            const unsigned short* srcA =                                      \
                Xpre + ((size_t)(kt) * 512 + GA) * 256;                       \
            __builtin_amdgcn_global_load_lds(                                 \
                (gvoid_t*)(srcA + tid * 8),                                   \
                (svoid_t*)(&As[(buf) * 2048 + tid * 8]), 16, 0, 0);           \
            __builtin_amdgcn_global_load_lds(                                 \
                (gvoid_t*)(srcA + 1024 + tid * 8),                            \
                (svoid_t*)(&As[(buf) * 2048 + 1024 + tid * 8]), 16, 0, 0);    \
            if (!diag) {                                                      \
                const unsigned short* srcB =                                  \
                    Xpre + ((size_t)(kt) * 512 + GB) * 256;                   \
                __builtin_amdgcn_global_load_lds(                             \
                    (gvoid_t*)(srcB + tid * 8),                               \
                    (svoid_t*)(&Bs[(buf) * 2048 + tid * 8]), 16, 0, 0);       \
                __builtin_amdgcn_global_load_lds(                             \
                    (gvoid_t*)(srcB + 1024 + tid * 8),                        \
                    (svoid_t*)(&Bs[(buf) * 2048 + 1024 + tid * 8]), 16, 0, 0);\
            }                                                                 \
        } while (0)

    const int physA = (quad ^ (m15 & 3)) * 8;   // un-swizzled chunk (shorts)

    STAGE(0, 0);
    for (int kt = 0; kt < NKT; ++kt) {
        const int cur = kt & 1;
        __syncthreads();                      // 2-wave sync; drains prev loads
        if (kt + 1 < NKT) STAGE(cur ^ 1, kt + 1);

        short8 a[4], b[2];
        #pragma unroll
        for (int tt = 0; tt < 4; ++tt) {
            const int rla = tt * 16 + m15;
            a[tt] = *(const short8*)(&As[cur * 2048 + rla * 32 + physA]);
        }
        #pragma unroll
        for (int tt = 0; tt < 2; ++tt) {
            const int rlb = wave * 32 + tt * 16 + m15;
            b[tt] = *(const short8*)(&Bbase[cur * 2048 + rlb * 32 + physA]);
        }
        #pragma unroll
        for (int tm = 0; tm < 4; ++tm)
            #pragma unroll
            for (int tn = 0; tn < 2; ++tn)
                acc[tm][tn] = __builtin_amdgcn_mfma_f32_16x16x32_bf16(
                    a[tm], b[tn], acc[tm][tn], 0, 0, 0);
    }
    #undef STAGE

    // Epilogue: C/D map col=lane&15, row=quad*4+reg (m89/m91 verified)
    float sa = 0.f, ss = 0.f;
    #pragma unroll
    for (int tm = 0; tm < 4; ++tm) {
        #pragma unroll
        for (int rr = 0; rr < 4; ++rr) {
            const int i = bm0 + tm * 16 + quad * 4 + rr;
            const float2 mi = meta[i];
            const int ydi = __float_as_int(mi.y);
            const int di = ydi & 3, yi = ydi >> 2;
            #pragma unroll
            for (int tn = 0; tn < 2; ++tn) {
                if (diag) {
                    if (di < dj[tn]) {
                        const float d2   = mi.x + sqj[tn] - 2.0f * acc[tm][tn][rr];
                        const float dist = sqrtf(fmaxf(d2, 0.f));
                        if (yi == yj[tn])     sa += dist;
                        else if (yi < yj[tn]) ss += fmaxf(0.f, 1.f - dist);
                    }
                } else {
                    // fold both orientations (dist symmetric; exactly one
                    // orientation has d_lt when ds differ)
                    if (di != dj[tn]) {
                        const float d2   = mi.x + sqj[tn] - 2.0f * acc[tm][tn][rr];
                        const float dist = sqrtf(fmaxf(d2, 0.f));
                        if (yi == yj[tn]) {
                            sa += dist;
                        } else {
                            const bool take = (di < dj[tn]) ? (yi < yj[tn])
                                                            : (yj[tn] < yi);
                            if (take) ss += fmaxf(0.f, 1.f - dist);
                        }
                    }
                }
            }
        }
    }
    #pragma unroll
    for (int off = 32; off; off >>= 1) {
        sa += __shfl_xor(sa, off);
        ss += __shfl_xor(ss, off);
    }
    if (lane == 0) { red[wave] = sa; red[2 + wave] = ss; }
    __syncthreads();
    if (tid == 0) {
        const float tsa = red[0] + red[1];
        const float tss = red[2] + red[3];
        const int nc = *ncls, nd = *ndom;
        const float n_sa = (float)(nc * (nd * (nd - 1) / 2));
        const float n_s  = (float)((nc * (nc - 1) / 2) * (nd * (nd - 1) / 2));
        atomicAdd(out + 0, tsa * 0.5f / n_sa);
        atomicAdd(out + 1, tss * 0.5f / n_s);
    }
}

extern "C" void kernel_launch(void* const* d_in, const int* in_sizes, int n_in,
                              void* d_out, int out_size, void* d_ws, size_t ws_size,
                              hipStream_t stream) {
    (void)in_sizes; (void)n_in; (void)out_size; (void)ws_size;
    const float* X  = (const float*)d_in[0];
    const int*   ds = (const int*)d_in[1];
    const int*   y  = (const int*)d_in[2];
    const int*   nc = (const int*)d_in[3];
    const int*   nd = (const int*)d_in[4];
    float* out = (float*)d_out;

    unsigned short* Xpre = (unsigned short*)d_ws;                       // 4 MB
    float2* meta = (float2*)((char*)d_ws + (size_t)NROW * DIM * 2);     // 32 KB

    prep_kernel<<<NROW / 4, 256, 0, stream>>>(X, ds, y, Xpre, meta, out);
    ccsa_kernel<<<NTRI, 128, 0, stream>>>(Xpre, meta, nc, nd, out);
}

// Round 9
// 126.505 us; speedup vs baseline: 1.0858x; 1.0858x over previous
//
#include <hip/hip_runtime.h>
#include <hip/hip_bf16.h>
#include <stdint.h>

#define NROW 4096
#define DIM  512
#define BT   64                        // block tile 64x64
#define NT64 (NROW / BT)               // 64
#define NTRI (NT64 * (NT64 + 1) / 2)   // 2080 triangular blocks
#define PANEL (BT * DIM)               // 32768 B per fp8 panel

typedef __attribute__((ext_vector_type(4))) float floatx4;  // MFMA 16x16 C/D

typedef const __attribute__((address_space(1))) void gvoid_t;
typedef __attribute__((address_space(3))) void       svoid_t;

// Panel-major pre-swizzled fp8 layout: panel g = row/64 (32 KB contiguous).
// Within a panel, row r (0..63) occupies 512 B; logical 8-B k-chunk c
// (c = k/8, 0..63) is stored at physical chunk p = c ^ r.  Frag reads then
// spread a quad's 16 lanes across all 32 banks (conflict-free), and staging
// is a plain linear 32-KB copy.
__global__ __launch_bounds__(256) void prep_kernel(
    const float* __restrict__ X, const int* __restrict__ ds,
    const int* __restrict__ y, unsigned char* __restrict__ Xq,
    float2* __restrict__ meta, float* __restrict__ out)
{
    const int wave = threadIdx.x >> 6;
    const int lane = threadIdx.x & 63;
    const int row  = blockIdx.x * 4 + wave;
    const float4* xr = (const float4*)(X + (size_t)row * DIM);
    float4 v0 = xr[2 * lane];                    // floats 8*lane .. 8*lane+3
    float4 v1 = xr[2 * lane + 1];                // floats 8*lane+4 .. +7
    float s = v0.x*v0.x + v0.y*v0.y + v0.z*v0.z + v0.w*v0.w
            + v1.x*v1.x + v1.y*v1.y + v1.z*v1.z + v1.w*v1.w;
    // pack 8 floats -> 8 fp8 e4m3 bytes (RNE, saturating), k ascending
    int q0 = __builtin_amdgcn_cvt_pk_fp8_f32(v0.x, v0.y, 0, false);
    q0     = __builtin_amdgcn_cvt_pk_fp8_f32(v0.z, v0.w, q0, true);
    int q1 = __builtin_amdgcn_cvt_pk_fp8_f32(v1.x, v1.y, 0, false);
    q1     = __builtin_amdgcn_cvt_pk_fp8_f32(v1.z, v1.w, q1, true);
    const int g  = row >> 6;
    const int r6 = row & 63;
    const int p  = lane ^ r6;                    // logical chunk = lane
    *(uint2*)(Xq + (size_t)g * PANEL + r6 * 512 + p * 8) =
        make_uint2((unsigned)q0, (unsigned)q1);
    #pragma unroll
    for (int off = 32; off; off >>= 1) s += __shfl_xor(s, off);
    if (lane == 0)
        meta[row] = make_float2(s, __int_as_float(y[row] * 4 + ds[row]));
    if (blockIdx.x == 0 && threadIdx.x < 2) out[threadIdx.x] = 0.0f;
}

// Triangular 64x64 Gram tiles, 256 threads (4 waves, 32x32 each via fp8
// 16x16x32 MFMA).  FULL-K staged once (A,B panels 32 KB each), ONE
// __syncthreads per block, then a barrier-free LDS+MFMA K-loop.
// 64.03 KB LDS -> 2 blocks/CU; stage of one block overlaps compute of the
// other.  This removes the per-kt vmcnt(0) barrier drain that bounded
// R2/R5/R7 (and the 4-way bank conflicts measured in R8).
__global__ __launch_bounds__(256, 2) void ccsa_kernel(
    const unsigned char* __restrict__ Xq, const float2* __restrict__ meta,
    const int* __restrict__ ncls, const int* __restrict__ ndom,
    float* __restrict__ out)
{
    __shared__ __align__(16) unsigned char As[PANEL];   // 32 KB
    __shared__ __align__(16) unsigned char Bs[PANEL];   // 32 KB
    __shared__ float red[8];

    // triangular decode: block t -> (it <= jt) on the 64-tile lattice
    const int t = blockIdx.x;
    int r = (int)((sqrtf(8.0f * (float)t + 1.0f) - 1.0f) * 0.5f);
    while ((r + 1) * (r + 2) / 2 <= t) ++r;
    while (r * (r + 1) / 2 > t) --r;
    const int jt   = r;
    const int it   = t - r * (r + 1) / 2;
    const bool diag = (it == jt);
    const int i0 = it * BT;
    const int j0 = jt * BT;

    const int tid    = threadIdx.x;
    const int wave   = tid >> 6;
    const int lane   = tid & 63;
    const int warp_m = wave >> 1;       // 0..1 : 32-row band
    const int warp_n = wave & 1;        // 0..1 : 32-col band
    const int m15    = lane & 15;
    const int quad   = lane >> 4;

    // j-side metadata, loop-invariant
    float sqj[2]; int yj[2], dj[2];
    #pragma unroll
    for (int tn = 0; tn < 2; ++tn) {
        const float2 mj = meta[j0 + warp_n * 32 + tn * 16 + m15];
        sqj[tn] = mj.x;
        const int ydj = __float_as_int(mj.y);
        dj[tn] = ydj & 3; yj[tn] = ydj >> 2;
    }

    floatx4 acc[2][2];
    #pragma unroll
    for (int a = 0; a < 2; ++a)
        #pragma unroll
        for (int b = 0; b < 2; ++b)
            acc[a][b] = (floatx4){0.f, 0.f, 0.f, 0.f};

    // single full-K staging: linear 32-KB copies (16-B per thread per pass)
    const unsigned char* srcA = Xq + (size_t)it * PANEL;
    const unsigned char* srcB = Xq + (size_t)jt * PANEL;
    #pragma unroll
    for (int s = 0; s < 8; ++s) {
        __builtin_amdgcn_global_load_lds(
            (gvoid_t*)(srcA + s * 4096 + tid * 16),
            (svoid_t*)(&As[s * 4096 + tid * 16]), 16, 0, 0);
        if (!diag)
            __builtin_amdgcn_global_load_lds(
                (gvoid_t*)(srcB + s * 4096 + tid * 16),
                (svoid_t*)(&Bs[s * 4096 + tid * 16]), 16, 0, 0);
    }
    __syncthreads();                    // the ONLY pre-epilogue barrier

    const unsigned char* Bb = diag ? As : Bs;  // diag: A-tile == B-tile

    // per-lane fragment rows (panel-local 0..63)
    const int rowa0 = warp_m * 32 + m15;
    const int rowa1 = warp_m * 32 + 16 + m15;
    const int rowb0 = warp_n * 32 + m15;
    const int rowb1 = warp_n * 32 + 16 + m15;

    // barrier-free K-loop: 16 x (4 ds_read_b64 + 4 MFMA) per wave
    #pragma unroll
    for (int kt = 0; kt < 16; ++kt) {
        const int c = kt * 4 + quad;                 // logical 8-B chunk
        const long a0 = *(const long*)(&As[rowa0 * 512 + (c ^ rowa0) * 8]);
        const long a1 = *(const long*)(&As[rowa1 * 512 + (c ^ rowa1) * 8]);
        const long b0 = *(const long*)(&Bb[rowb0 * 512 + (c ^ rowb0) * 8]);
        const long b1 = *(const long*)(&Bb[rowb1 * 512 + (c ^ rowb1) * 8]);
        acc[0][0] = __builtin_amdgcn_mfma_f32_16x16x32_fp8_fp8(a0, b0, acc[0][0], 0, 0, 0);
        acc[0][1] = __builtin_amdgcn_mfma_f32_16x16x32_fp8_fp8(a0, b1, acc[0][1], 0, 0, 0);
        acc[1][0] = __builtin_amdgcn_mfma_f32_16x16x32_fp8_fp8(a1, b0, acc[1][0], 0, 0, 0);
        acc[1][1] = __builtin_amdgcn_mfma_f32_16x16x32_fp8_fp8(a1, b1, acc[1][1], 0, 0, 0);
    }

    // Epilogue: C/D map col=lane&15, row=quad*4+reg (dtype-independent)
    float sa = 0.f, ss = 0.f;
    #pragma unroll
    for (int tm = 0; tm < 2; ++tm) {
        #pragma unroll
        for (int rr = 0; rr < 4; ++rr) {
            const int i = i0 + warp_m * 32 + tm * 16 + quad * 4 + rr;
            const float2 mi = meta[i];
            const int ydi = __float_as_int(mi.y);
            const int di = ydi & 3, yi = ydi >> 2;
            #pragma unroll
            for (int tn = 0; tn < 2; ++tn) {
                if (diag) {
                    if (di < dj[tn]) {
                        const float d2   = mi.x + sqj[tn] - 2.0f * acc[tm][tn][rr];
                        const float dist = sqrtf(fmaxf(d2, 0.f));
                        if (yi == yj[tn])     sa += dist;
                        else if (yi < yj[tn]) ss += fmaxf(0.f, 1.f - dist);
                    }
                } else {
                    // fold both orientations (dist symmetric; exactly one
                    // orientation has d_lt when ds differ)
                    if (di != dj[tn]) {
                        const float d2   = mi.x + sqj[tn] - 2.0f * acc[tm][tn][rr];
                        const float dist = sqrtf(fmaxf(d2, 0.f));
                        if (yi == yj[tn]) {
                            sa += dist;
                        } else {
                            const bool take = (di < dj[tn]) ? (yi < yj[tn])
                                                            : (yj[tn] < yi);
                            if (take) ss += fmaxf(0.f, 1.f - dist);
                        }
                    }
                }
            }
        }
    }
    #pragma unroll
    for (int off = 32; off; off >>= 1) {
        sa += __shfl_xor(sa, off);
        ss += __shfl_xor(ss, off);
    }
    if (lane == 0) { red[wave] = sa; red[4 + wave] = ss; }
    __syncthreads();
    if (tid == 0) {
        const float tsa = red[0] + red[1] + red[2] + red[3];
        const float tss = red[4] + red[5] + red[6] + red[7];
        const int nc = *ncls, nd = *ndom;
        const float n_sa = (float)(nc * (nd * (nd - 1) / 2));
        const float n_s  = (float)((nc * (nc - 1) / 2) * (nd * (nd - 1) / 2));
        atomicAdd(out + 0, tsa * 0.5f / n_sa);
        atomicAdd(out + 1, tss * 0.5f / n_s);
    }
}

extern "C" void kernel_launch(void* const* d_in, const int* in_sizes, int n_in,
                              void* d_out, int out_size, void* d_ws, size_t ws_size,
                              hipStream_t stream) {
    (void)in_sizes; (void)n_in; (void)out_size; (void)ws_size;
    const float* X  = (const float*)d_in[0];
    const int*   ds = (const int*)d_in[1];
    const int*   y  = (const int*)d_in[2];
    const int*   nc = (const int*)d_in[3];
    const int*   nd = (const int*)d_in[4];
    float* out = (float*)d_out;

    unsigned char* Xq = (unsigned char*)d_ws;                      // 2 MB fp8
    float2* meta = (float2*)((char*)d_ws + (size_t)NT64 * PANEL);  // 32 KB

    prep_kernel<<<NROW / 4, 256, 0, stream>>>(X, ds, y, Xq, meta, out);
    ccsa_kernel<<<NTRI, 256, 0, stream>>>(Xq, meta, nc, nd, out);
}

// Round 10
// 97.338 us; speedup vs baseline: 1.4112x; 1.2996x over previous
//
#include <hip/hip_runtime.h>
#include <hip/hip_bf16.h>
#include <stdint.h>

#define NROW 4096
#define DIM  512
#define BM   128
#define BN   128
#define BKE  128                 // K elements per round (fp8 bytes)
#define NKT  (DIM / BKE)         // 4 rounds
#define PANEL_KT (BM * BKE)      // 16384 B staged per panel per round

typedef __attribute__((ext_vector_type(4))) float floatx4;  // MFMA 16x16 C/D

typedef const __attribute__((address_space(1))) void gvoid_t;
typedef __attribute__((address_space(3))) void       svoid_t;

// fp8 kt-major pre-swizzled layout:
//   slab (kt=k/128, G=row/8) of 8 rows x 128 B, address
//   ((kt*512 + G)*8 + (row&7))*128 + phys8*8, where the logical 8-B
//   k-subchunk c (0..15) of the row sits at phys8 = c ^ (row & 15).
//   -> A 128-row panel's kt-slab is 16 KB fully contiguous (staging =
//      base + tid*16), and a quad's 16 b64 frag reads (phys8 = c ^ m15)
//      cover all 32 banks exactly once: strictly conflict-free.
// meta[row] = {sq_fp32, bits(y*4+ds)}.
__global__ __launch_bounds__(256) void prep_kernel(
    const float* __restrict__ X, const int* __restrict__ ds,
    const int* __restrict__ y, unsigned char* __restrict__ Xq,
    float2* __restrict__ meta, float* __restrict__ out)
{
    const int wave = threadIdx.x >> 6;
    const int lane = threadIdx.x & 63;
    const int row  = blockIdx.x * 4 + wave;
    const float4* xr = (const float4*)(X + (size_t)row * DIM);
    float4 v0 = xr[2 * lane];                    // floats 8*lane .. +3
    float4 v1 = xr[2 * lane + 1];                // floats 8*lane+4 .. +7
    float s = v0.x*v0.x + v0.y*v0.y + v0.z*v0.z + v0.w*v0.w
            + v1.x*v1.x + v1.y*v1.y + v1.z*v1.z + v1.w*v1.w;
    int q0 = __builtin_amdgcn_cvt_pk_fp8_f32(v0.x, v0.y, 0, false);
    q0     = __builtin_amdgcn_cvt_pk_fp8_f32(v0.z, v0.w, q0, true);
    int q1 = __builtin_amdgcn_cvt_pk_fp8_f32(v1.x, v1.y, 0, false);
    q1     = __builtin_amdgcn_cvt_pk_fp8_f32(v1.z, v1.w, q1, true);
    const int g8  = row >> 3;
    const int l3r = row & 7;
    const int kt  = lane >> 4;                   // k/128
    const int c   = lane & 15;                   // logical 8-B subchunk
    const int p8  = c ^ (row & 15);
    *(uint2*)(Xq + ((size_t)(kt * 512 + g8) * 8 + l3r) * 128 + p8 * 8) =
        make_uint2((unsigned)q0, (unsigned)q1);
    #pragma unroll
    for (int off = 32; off; off >>= 1) s += __shfl_xor(s, off);
    if (lane == 0)
        meta[row] = make_float2(s, __int_as_float(y[row] * 4 + ds[row]));
    if (blockIdx.x == 0 && threadIdx.x < 2) out[threadIdx.x] = 0.0f;
}

// R5 structure, fp8 dtype, BKE=128: triangular 128x128 Gram tiles, 512
// threads (8 waves 2x4, each 64x32 via 4x2 16x16x32 fp8 MFMAs), 64 KB LDS
// double-buffer, single barrier per round, only 4 rounds (vs R5's 8) and
// half R5's staged bytes at the same MFMA count.
__global__ __launch_bounds__(512, 4) void ccsa_kernel(
    const unsigned char* __restrict__ Xq, const float2* __restrict__ meta,
    const int* __restrict__ ncls, const int* __restrict__ ndom,
    float* __restrict__ out)
{
    __shared__ __align__(16) unsigned char As[2 * PANEL_KT];  // 32 KB
    __shared__ __align__(16) unsigned char Bs[2 * PANEL_KT];  // 32 KB
    __shared__ float red[16];

    // triangular decode: block t -> (bi_t <= bj_t), 528 blocks
    const int t = blockIdx.x;
    int r = (int)((sqrtf(8.0f * (float)t + 1.0f) - 1.0f) * 0.5f);
    while ((r + 1) * (r + 2) / 2 <= t) ++r;
    while (r * (r + 1) / 2 > t) --r;
    const int bj_t = r;
    const int bi_t = t - r * (r + 1) / 2;
    const bool diag = (bi_t == bj_t);
    const int bm0 = bi_t * BM;
    const int bn0 = bj_t * BN;
    const int GA = bm0 >> 3;
    const int GB = bn0 >> 3;

    const int tid    = threadIdx.x;
    const int wave   = tid >> 6;
    const int lane   = tid & 63;
    const int warp_m = wave >> 2;       // 0..1 : 64-row band
    const int warp_n = wave & 3;        // 0..3 : 32-col band
    const int m15    = lane & 15;
    const int quad   = lane >> 4;

    // j-side metadata, loop-invariant
    float sqj[2]; int yj[2], dj[2];
    #pragma unroll
    for (int tn = 0; tn < 2; ++tn) {
        const float2 mj = meta[bn0 + warp_n * 32 + tn * 16 + m15];
        sqj[tn] = mj.x;
        const int ydj = __float_as_int(mj.y);
        dj[tn] = ydj & 3; yj[tn] = ydj >> 2;
    }

    floatx4 acc[4][2];
    #pragma unroll
    for (int a = 0; a < 4; ++a)
        #pragma unroll
        for (int b = 0; b < 2; ++b)
            acc[a][b] = (floatx4){0.f, 0.f, 0.f, 0.f};

    const unsigned char* Bb = diag ? As : Bs;   // diag: A-tile == B-tile

    // staging: panel kt-slab is 16 KB contiguous; 512 thr x 2 x 16 B.
    #define STAGE(buf, kt)                                                    \
        do {                                                                  \
            const unsigned char* srcA =                                       \
                Xq + (size_t)((kt) * 512 + GA) * 1024;                        \
            __builtin_amdgcn_global_load_lds(                                 \
                (gvoid_t*)(srcA + tid * 16),                                  \
                (svoid_t*)(&As[(buf) * PANEL_KT + tid * 16]), 16, 0, 0);      \
            __builtin_amdgcn_global_load_lds(                                 \
                (gvoid_t*)(srcA + 8192 + tid * 16),                           \
                (svoid_t*)(&As[(buf) * PANEL_KT + 8192 + tid * 16]),          \
                16, 0, 0);                                                    \
            if (!diag) {                                                      \
                const unsigned char* srcB =                                   \
                    Xq + (size_t)((kt) * 512 + GB) * 1024;                    \
                __builtin_amdgcn_global_load_lds(                             \
                    (gvoid_t*)(srcB + tid * 16),                              \
                    (svoid_t*)(&Bs[(buf) * PANEL_KT + tid * 16]), 16, 0, 0);  \
                __builtin_amdgcn_global_load_lds(                             \
                    (gvoid_t*)(srcB + 8192 + tid * 16),                       \
                    (svoid_t*)(&Bs[(buf) * PANEL_KT + 8192 + tid * 16]),      \
                    16, 0, 0);                                                \
            }                                                                 \
        } while (0)

    // frag rows (panel-local); row&15 == m15 for all -> swz = m15
    const int rla0 = (warp_m * 64 +  0 + m15) * 128;
    const int rla1 = (warp_m * 64 + 16 + m15) * 128;
    const int rla2 = (warp_m * 64 + 32 + m15) * 128;
    const int rla3 = (warp_m * 64 + 48 + m15) * 128;
    const int rlb0 = (warp_n * 32 +  0 + m15) * 128;
    const int rlb1 = (warp_n * 32 + 16 + m15) * 128;

    STAGE(0, 0);
    for (int kt = 0; kt < NKT; ++kt) {
        const int cur = kt & 1;
        __syncthreads();                      // drains prev-phase loads
        if (kt + 1 < NKT) STAGE(cur ^ 1, kt + 1);
        const int cb = cur * PANEL_KT;

        #pragma unroll
        for (int s = 0; s < 4; ++s) {         // four K=32 steps per round
            const int ph = ((s * 4 + quad) ^ m15) * 8;   // un-swizzle, bytes
            const long a0 = *(const long*)(&As[cb + rla0 + ph]);
            const long a1 = *(const long*)(&As[cb + rla1 + ph]);
            const long a2 = *(const long*)(&As[cb + rla2 + ph]);
            const long a3 = *(const long*)(&As[cb + rla3 + ph]);
            const long b0 = *(const long*)(&Bb[cb + rlb0 + ph]);
            const long b1 = *(const long*)(&Bb[cb + rlb1 + ph]);
            acc[0][0] = __builtin_amdgcn_mfma_f32_16x16x32_fp8_fp8(a0, b0, acc[0][0], 0, 0, 0);
            acc[0][1] = __builtin_amdgcn_mfma_f32_16x16x32_fp8_fp8(a0, b1, acc[0][1], 0, 0, 0);
            acc[1][0] = __builtin_amdgcn_mfma_f32_16x16x32_fp8_fp8(a1, b0, acc[1][0], 0, 0, 0);
            acc[1][1] = __builtin_amdgcn_mfma_f32_16x16x32_fp8_fp8(a1, b1, acc[1][1], 0, 0, 0);
            acc[2][0] = __builtin_amdgcn_mfma_f32_16x16x32_fp8_fp8(a2, b0, acc[2][0], 0, 0, 0);
            acc[2][1] = __builtin_amdgcn_mfma_f32_16x16x32_fp8_fp8(a2, b1, acc[2][1], 0, 0, 0);
            acc[3][0] = __builtin_amdgcn_mfma_f32_16x16x32_fp8_fp8(a3, b0, acc[3][0], 0, 0, 0);
            acc[3][1] = __builtin_amdgcn_mfma_f32_16x16x32_fp8_fp8(a3, b1, acc[3][1], 0, 0, 0);
        }
    }
    #undef STAGE

    // Epilogue: C/D map col=lane&15, row=quad*4+reg (dtype-independent)
    float sa = 0.f, ss = 0.f;
    #pragma unroll
    for (int tm = 0; tm < 4; ++tm) {
        #pragma unroll
        for (int rr = 0; rr < 4; ++rr) {
            const int i = bm0 + warp_m * 64 + tm * 16 + quad * 4 + rr;
            const float2 mi = meta[i];
            const int ydi = __float_as_int(mi.y);
            const int di = ydi & 3, yi = ydi >> 2;
            #pragma unroll
            for (int tn = 0; tn < 2; ++tn) {
                if (diag) {
                    if (di < dj[tn]) {
                        const float d2   = mi.x + sqj[tn] - 2.0f * acc[tm][tn][rr];
                        const float dist = sqrtf(fmaxf(d2, 0.f));
                        if (yi == yj[tn])     sa += dist;
                        else if (yi < yj[tn]) ss += fmaxf(0.f, 1.f - dist);
                    }
                } else {
                    // fold both orientations (dist symmetric; exactly one
                    // orientation has d_lt when ds differ)
                    if (di != dj[tn]) {
                        const float d2   = mi.x + sqj[tn] - 2.0f * acc[tm][tn][rr];
                        const float dist = sqrtf(fmaxf(d2, 0.f));
                        if (yi == yj[tn]) {
                            sa += dist;
                        } else {
                            const bool take = (di < dj[tn]) ? (yi < yj[tn])
                                                            : (yj[tn] < yi);
                            if (take) ss += fmaxf(0.f, 1.f - dist);
                        }
                    }
                }
            }
        }
    }
    #pragma unroll
    for (int off = 32; off; off >>= 1) {
        sa += __shfl_xor(sa, off);
        ss += __shfl_xor(ss, off);
    }
    if (lane == 0) { red[wave] = sa; red[8 + wave] = ss; }
    __syncthreads();
    if (tid == 0) {
        float tsa = 0.f, tss = 0.f;
        #pragma unroll
        for (int w = 0; w < 8; ++w) { tsa += red[w]; tss += red[8 + w]; }
        const int nc = *ncls, nd = *ndom;
        const float n_sa = (float)(nc * (nd * (nd - 1) / 2));
        const float n_s  = (float)((nc * (nc - 1) / 2) * (nd * (nd - 1) / 2));
        atomicAdd(out + 0, tsa * 0.5f / n_sa);
        atomicAdd(out + 1, tss * 0.5f / n_s);
    }
}

extern "C" void kernel_launch(void* const* d_in, const int* in_sizes, int n_in,
                              void* d_out, int out_size, void* d_ws, size_t ws_size,
                              hipStream_t stream) {
    (void)in_sizes; (void)n_in; (void)out_size; (void)ws_size;
    const float* X  = (const float*)d_in[0];
    const int*   ds = (const int*)d_in[1];
    const int*   y  = (const int*)d_in[2];
    const int*   nc = (const int*)d_in[3];
    const int*   nd = (const int*)d_in[4];
    float* out = (float*)d_out;

    unsigned char* Xq = (unsigned char*)d_ws;                          // 2 MB
    float2* meta = (float2*)((char*)d_ws + (size_t)NROW * DIM);        // 32 KB

    prep_kernel<<<NROW / 4, 256, 0, stream>>>(X, ds, y, Xq, meta, out);
    const int ntiles = NROW / BM;                                      // 32
    const int nblocks = ntiles * (ntiles + 1) / 2;                     // 528
    ccsa_kernel<<<nblocks, 512, 0, stream>>>(Xq, meta, nc, nd, out);
}